// Round 9
// baseline (1503.905 us; speedup 1.0000x reference)
//
#include <hip/hip_runtime.h>

#define NN 50000
#define NE 600000
#define DIM 128
#define NLAYERS 8
#define NCLASSES 10
#define NGRAPHS 64
#define BN_EPS 1e-5f
#define SLOPE 0.01f

typedef __attribute__((ext_vector_type(8))) short bf16x8;
typedef __attribute__((ext_vector_type(4))) float f32x4;

__device__ __forceinline__ float lrelu(float v) { return v > 0.f ? v : SLOPE * v; }

__device__ __forceinline__ unsigned short f2bf(float x) {
    unsigned u = __builtin_bit_cast(unsigned, x);
    unsigned r = (u + 0x7FFFu + ((u >> 16) & 1u)) >> 16;
    return (unsigned short)r;
}
__device__ __forceinline__ float bf2f(unsigned short h) {
    return __builtin_bit_cast(float, (unsigned)h << 16);
}
// split x into hi+lo bf16 pair: hi = bf16(x), lo = bf16(x - hi)
__device__ __forceinline__ void split8(const float* __restrict__ p, bf16x8& hi, bf16x8& lo) {
#pragma unroll
    for (int j = 0; j < 8; j++) {
        float x = p[j];
        unsigned short h = f2bf(x);
        hi[j] = (short)h;
        lo[j] = (short)f2bf(x - bf2f(h));
    }
}

// ---------------- CSR build: degree histogram
__global__ __launch_bounds__(256) void degree_kernel(const int* __restrict__ edges,
                                                     int* __restrict__ counts) {
    int e = blockIdx.x * 256 + threadIdx.x;
    if (e >= NE) return;
    atomicAdd(&counts[edges[NE + e]], 1);
}

// ---------------- CSR build: exclusive scan of counts -> offsets (single block)
__global__ __launch_bounds__(1024) void scan_kernel(const int* __restrict__ counts,
                                                    int* __restrict__ offsets) {
    __shared__ int wsum[16];
    __shared__ int carry;
    int lane = threadIdx.x & 63, wid = threadIdx.x >> 6;
    if (threadIdx.x == 0) { carry = 0; offsets[0] = 0; }
    __syncthreads();
    for (int base = 0; base < NN; base += 1024) {
        int i = base + threadIdx.x;
        int v = (i < NN) ? counts[i] : 0;
        int s = v;
#pragma unroll
        for (int o = 1; o < 64; o <<= 1) {
            int t = __shfl_up(s, o);
            if (lane >= o) s += t;
        }
        if (lane == 63) wsum[wid] = s;
        __syncthreads();
        if (wid == 0 && lane < 16) {
            int w = wsum[lane];
            int sw = w;
#pragma unroll
            for (int o = 1; o < 16; o <<= 1) {
                int t = __shfl_up(sw, o);
                if (lane >= o) sw += t;
            }
            wsum[lane] = sw - w;  // exclusive
        }
        __syncthreads();
        int incl = s + wsum[wid] + carry;
        if (i < NN) offsets[i + 1] = incl;
        __syncthreads();
        if (threadIdx.x == 1023) carry = incl;
        __syncthreads();
    }
}

// ---------------- CSR build: fill src lists
__global__ __launch_bounds__(256) void fill_kernel(const int* __restrict__ edges,
                                                   int* __restrict__ cursor,
                                                   int* __restrict__ csr_src) {
    int e = blockIdx.x * 256 + threadIdx.x;
    if (e >= NE) return;
    int d = edges[NE + e];
    int p = atomicAdd(&cursor[d], 1);
    csr_src[p] = edges[e];
}

// ---------------- weight prep: hi/lo bf16 of W^T.  Wt[mat][n][k] = bf16(W[k][n])
__global__ __launch_bounds__(256) void wprep_kernel(const float* __restrict__ W1s,
                                                    const float* __restrict__ W2s,
                                                    unsigned short* __restrict__ Wh,
                                                    unsigned short* __restrict__ Wl) {
    int gid = blockIdx.x * 256 + threadIdx.x;  // 16 * 16384
    if (gid >= 16 * 16384) return;
    int mat = gid >> 14;
    int idx = gid & 16383;
    int n = idx >> 7, k = idx & 127;
    int layer = mat >> 1, which = mat & 1;
    const float* src = which ? (W2s + (size_t)layer * 16384) : (W1s + (size_t)layer * 16384);
    float x = src[k * DIM + n];
    unsigned short h = f2bf(x);
    Wh[gid] = h;
    Wl[gid] = f2bf(x - bf2f(h));
}

// ---------------- gather (+ fused BN/lrelu): hz[i] = f(z[i]) + sum_j f(z[j]), f32 out
template <int BN>
__global__ __launch_bounds__(256) void gather_kernel(const float* __restrict__ Zin,
                                                     const float* __restrict__ ss,
                                                     const int* __restrict__ offsets,
                                                     const int* __restrict__ csr_src,
                                                     float* __restrict__ hz) {
    int node = blockIdx.x * 4 + (threadIdx.x >> 6);
    if (node >= NN) return;
    int lane = threadIdx.x & 63;
    size_t coloff = (size_t)lane * 2;
    float2 sc, sh;
    if (BN) {
        sc = *(const float2*)(ss + lane * 2);
        sh = *(const float2*)(ss + DIM + lane * 2);
    }
    int beg = offsets[node], end = offsets[node + 1];
    float2 v = *(const float2*)(Zin + (size_t)node * DIM + coloff);
    float ax, ay;
    if (BN) { ax = lrelu(v.x * sc.x + sh.x); ay = lrelu(v.y * sc.y + sh.y); }
    else    { ax = v.x; ay = v.y; }
    for (int e = beg; e < end; e++) {
        int s = csr_src[e];
        float2 w = *(const float2*)(Zin + (size_t)s * DIM + coloff);
        if (BN) { ax += lrelu(w.x * sc.x + sh.x); ay += lrelu(w.y * sc.y + sh.y); }
        else    { ax += w.x; ay += w.y; }
    }
    float2 o; o.x = ax; o.y = ay;
    *(float2*)(hz + (size_t)node * DIM + coloff) = o;
}

// ---------------- fused MLP on matrix cores, split-bf16 (3-product) precision:
// Z = (lrelu(hz @ W1 + b1)) @ W2 + b2.  hz f32 in, Z f32 out, t1 f32 in LDS.
// 256 thr = 4 waves; wave owns 16 rows x 128 cols; t1 rows wave-private (no barriers).
__global__ __launch_bounds__(256) void mlp_mfma(const float* __restrict__ hz,
                                                const unsigned short* __restrict__ W1h,
                                                const unsigned short* __restrict__ W1l,
                                                const float* __restrict__ b1,
                                                const unsigned short* __restrict__ W2h,
                                                const unsigned short* __restrict__ W2l,
                                                const float* __restrict__ b2,
                                                float* __restrict__ Z) {
    __shared__ float t1[64][132];  // 528B pitch (16B-aligned, 2-way bank alias = free)
    int tid = threadIdx.x;
    int w = tid >> 6, l = tid & 63;
    int l15 = l & 15, kg = l >> 4;
    int rbase = blockIdx.x * 64 + w * 16;
    int mrow = rbase + l15;

    // A fragments (hi/lo) for GEMM1, direct from global f32
    bf16x8 ah[4], al[4];
#pragma unroll
    for (int kb = 0; kb < 4; kb++) {
        float buf[8];
        if (mrow < NN) {
            float4 v0 = *(const float4*)(hz + (size_t)mrow * DIM + kb * 32 + kg * 8);
            float4 v1 = *(const float4*)(hz + (size_t)mrow * DIM + kb * 32 + kg * 8 + 4);
            buf[0] = v0.x; buf[1] = v0.y; buf[2] = v0.z; buf[3] = v0.w;
            buf[4] = v1.x; buf[5] = v1.y; buf[6] = v1.z; buf[7] = v1.w;
        } else {
#pragma unroll
            for (int j = 0; j < 8; j++) buf[j] = 0.f;
        }
        split8(buf, ah[kb], al[kb]);
    }
    // GEMM1: t1 = lrelu(hz @ W1 + b1)   (C: row = kg*4+j, col = nt*16+l15)
#pragma unroll
    for (int nt = 0; nt < 8; nt++) {
        f32x4 acc = {0.f, 0.f, 0.f, 0.f};
#pragma unroll
        for (int kb = 0; kb < 4; kb++) {
            size_t woff = (size_t)(nt * 16 + l15) * DIM + kb * 32 + kg * 8;
            bf16x8 wh = *(const bf16x8*)(W1h + woff);
            bf16x8 wl = *(const bf16x8*)(W1l + woff);
            acc = __builtin_amdgcn_mfma_f32_16x16x32_bf16(ah[kb], wh, acc, 0, 0, 0);
            acc = __builtin_amdgcn_mfma_f32_16x16x32_bf16(ah[kb], wl, acc, 0, 0, 0);
            acc = __builtin_amdgcn_mfma_f32_16x16x32_bf16(al[kb], wh, acc, 0, 0, 0);
        }
        float bias = b1[nt * 16 + l15];
        int colw = nt * 16 + l15;
#pragma unroll
        for (int j = 0; j < 4; j++) {
            t1[w * 16 + kg * 4 + j][colw] = lrelu(acc[j] + bias);
        }
    }
    // A fragments for GEMM2 from LDS (wave-private rows; compiler waits lgkmcnt)
    bf16x8 a2h[4], a2l[4];
#pragma unroll
    for (int kb = 0; kb < 4; kb++) {
        split8(&t1[w * 16 + l15][kb * 32 + kg * 8], a2h[kb], a2l[kb]);
    }
    // GEMM2: Z = t1 @ W2 + b2
#pragma unroll
    for (int nt = 0; nt < 8; nt++) {
        f32x4 acc = {0.f, 0.f, 0.f, 0.f};
#pragma unroll
        for (int kb = 0; kb < 4; kb++) {
            size_t woff = (size_t)(nt * 16 + l15) * DIM + kb * 32 + kg * 8;
            bf16x8 wh = *(const bf16x8*)(W2h + woff);
            bf16x8 wl = *(const bf16x8*)(W2l + woff);
            acc = __builtin_amdgcn_mfma_f32_16x16x32_bf16(a2h[kb], wh, acc, 0, 0, 0);
            acc = __builtin_amdgcn_mfma_f32_16x16x32_bf16(a2h[kb], wl, acc, 0, 0, 0);
            acc = __builtin_amdgcn_mfma_f32_16x16x32_bf16(a2l[kb], wh, acc, 0, 0, 0);
        }
        float bias = b2[nt * 16 + l15];
#pragma unroll
        for (int j = 0; j < 4; j++) {
            int r = rbase + kg * 4 + j;
            if (r < NN) Z[(size_t)r * DIM + nt * 16 + l15] = acc[j] + bias;
        }
    }
}

// ---------------- BN stats: per-col sum & sumsq
__global__ __launch_bounds__(256) void bnstats_kernel(const float* __restrict__ Z,
                                                      float* __restrict__ stats) {
    int col = threadIdx.x & 127;
    int half = threadIdx.x >> 7;
    int stride = gridDim.x * 2;
    float s = 0.f, s2 = 0.f;
    for (int r = blockIdx.x * 2 + half; r < NN; r += stride) {
        float v = Z[(long long)r * DIM + col];
        s += v;
        s2 += v * v;
    }
    __shared__ float red[2][2][DIM];
    red[0][half][col] = s;
    red[1][half][col] = s2;
    __syncthreads();
    if (half == 0) {
        atomicAdd(&stats[col], red[0][0][col] + red[0][1][col]);
        atomicAdd(&stats[DIM + col], red[1][0][col] + red[1][1][col]);
    }
}

// ---------------- BN finalize
__global__ void bnfinalize_kernel(const float* __restrict__ stats,
                                  const float* __restrict__ gamma,
                                  const float* __restrict__ beta,
                                  float* __restrict__ ss) {
    int c = threadIdx.x;
    float mu = stats[c] * (1.f / NN);
    float var = stats[DIM + c] * (1.f / NN) - mu * mu;
    float sc = gamma[c] * rsqrtf(var + BN_EPS);
    ss[c] = sc;
    ss[DIM + c] = beta[c] - mu * sc;
}

// ---------------- graph start offsets (batch sorted)
__global__ void gstart_kernel(const int* __restrict__ batch, int* __restrict__ gs) {
    int g = threadIdx.x;
    if (g > NGRAPHS) return;
    if (g == NGRAPHS) { gs[g] = NN; return; }
    int lo = 0, hi = NN;
    while (lo < hi) {
        int mid = (lo + hi) >> 1;
        if (batch[mid] < g) lo = mid + 1; else hi = mid;
    }
    gs[g] = lo;
}

// ---------------- gumbel softmax per node with BN fold
__global__ __launch_bounds__(256) void softmaxc_kernel(const float* __restrict__ Z,
                                                       const float* __restrict__ ss,
                                                       const float* __restrict__ G,
                                                       float* __restrict__ C) {
    int node = blockIdx.x * 4 + (threadIdx.x >> 6);
    if (node >= NN) return;
    int lane = threadIdx.x & 63;
    size_t base = (size_t)node * DIM + lane * 2;
    float2 z = *(const float2*)(Z + base);
    float2 sc = *(const float2*)(ss + lane * 2);
    float2 sh = *(const float2*)(ss + DIM + lane * 2);
    float2 gv = *(const float2*)(G + base);
    float vx = z.x * sc.x + sh.x + gv.x;
    float vy = z.y * sc.y + sh.y + gv.y;
    float m = fmaxf(vx, vy);
#pragma unroll
    for (int o = 32; o >= 1; o >>= 1) m = fmaxf(m, __shfl_xor(m, o));
    float ex = __expf(vx - m), ey = __expf(vy - m);
    float s = ex + ey;
#pragma unroll
    for (int o = 32; o >= 1; o >>= 1) s += __shfl_xor(s, o);
    float inv = 1.f / s;
    float2 c;
    c.x = ex * inv;
    c.y = ey * inv;
    *(float2*)(C + base) = c;
}

// ---------------- pool: block per graph, contiguous column sums
__global__ __launch_bounds__(128) void pool_kernel(const float* __restrict__ C,
                                                   const int* __restrict__ gs,
                                                   float* __restrict__ pooled) {
    int g = blockIdx.x, col = threadIdx.x;
    int beg = gs[g], end = gs[g + 1];
    float a0 = 0.f, a1 = 0.f, a2 = 0.f, a3 = 0.f;
    int r = beg;
    for (; r + 4 <= end; r += 4) {
        a0 += C[(size_t)r * DIM + col];
        a1 += C[(size_t)(r + 1) * DIM + col];
        a2 += C[(size_t)(r + 2) * DIM + col];
        a3 += C[(size_t)(r + 3) * DIM + col];
    }
    for (; r < end; r++) a0 += C[(size_t)r * DIM + col];
    pooled[g * DIM + col] = (a0 + a1) + (a2 + a3);
}

// ---------------- dense head
__global__ __launch_bounds__(128) void head_kernel(const float* __restrict__ pooled,
                                                   const float* __restrict__ Wd1,
                                                   const float* __restrict__ bd1,
                                                   const float* __restrict__ Wd2,
                                                   const float* __restrict__ bd2,
                                                   float* __restrict__ out) {
    int g = blockIdx.x;
    int j = threadIdx.x;
    __shared__ float hid[DIM];
    __shared__ float logits[NCLASSES];
    float acc = bd1[j];
    for (int k = 0; k < DIM; k++) acc += pooled[g * DIM + k] * Wd1[k * DIM + j];
    hid[j] = lrelu(acc);
    __syncthreads();
    if (j < NCLASSES) {
        float a = bd2[j];
        for (int k = 0; k < DIM; k++) a += hid[k] * Wd2[k * NCLASSES + j];
        logits[j] = a;
    }
    __syncthreads();
    if (j == 0) {
        float m = -1e30f;
        for (int c = 0; c < NCLASSES; c++) m = fmaxf(m, logits[c]);
        float s = 0.f, e[NCLASSES];
        for (int c = 0; c < NCLASSES; c++) { e[c] = __expf(logits[c] - m); s += e[c]; }
        float inv = 1.f / s;
        for (int c = 0; c < NCLASSES; c++) out[g * NCLASSES + c] = e[c] * inv;
    }
}

extern "C" void kernel_launch(void* const* d_in, const int* in_sizes, int n_in,
                              void* d_out, int out_size, void* d_ws, size_t ws_size,
                              hipStream_t stream) {
    const float* x = (const float*)d_in[0];
    const int* edges = (const int*)d_in[1];
    const int* batch = (const int*)d_in[2];
    const float* gum = (const float*)d_in[3];
    const float* W1s = (const float*)d_in[4];
    const float* b1s = (const float*)d_in[5];
    const float* W2s = (const float*)d_in[6];
    const float* b2s = (const float*)d_in[7];
    const float* gammas = (const float*)d_in[8];
    const float* betas = (const float*)d_in[9];
    const float* Wd1 = (const float*)d_in[10];
    const float* bd1 = (const float*)d_in[11];
    const float* Wd2 = (const float*)d_in[12];
    const float* bd2 = (const float*)d_in[13];

    float* out = (float*)d_out;
    float* cout = out + NGRAPHS * NCLASSES;

    const size_t ND = (size_t)NN * DIM;
    float* ws = (float*)d_ws;
    float* z = ws;                                   // ND f32 (pre-BN layer output)
    float* hz = z + ND;                              // ND f32 (gather out / MLP in)
    unsigned short* Wh = (unsigned short*)(hz + ND); // 16*16384 bf16 (W^T hi)
    unsigned short* Wl = Wh + 16 * 16384;            // 16*16384 bf16 (W^T lo)
    float* stats8 = (float*)(Wl + 16 * 16384);       // 8 * 2*DIM
    float* ss8 = stats8 + NLAYERS * 2 * DIM;         // 8 * 2*DIM
    float* pooled = ss8 + NLAYERS * 2 * DIM;         // NGRAPHS*DIM
    int* counts = (int*)(pooled + NGRAPHS * DIM);    // NN
    int* offsets = counts + NN;                      // NN+1
    int* cursor = offsets + NN + 1;                  // NN
    int* csr_src = cursor + NN;                      // NE
    int* gs = csr_src + NE;                          // NGRAPHS+1

    const int MLP_BLOCKS = (NN + 63) / 64;
    const int EDGE_BLOCKS = (NE + 255) / 256;
    const int NODE_BLOCKS = (NN + 3) / 4;

    // ---- CSR build + weight prep (static per launch)
    hipMemsetAsync(counts, 0, NN * sizeof(int), stream);
    degree_kernel<<<EDGE_BLOCKS, 256, 0, stream>>>(edges, counts);
    scan_kernel<<<1, 1024, 0, stream>>>(counts, offsets);
    hipMemcpyAsync(cursor, offsets, NN * sizeof(int), hipMemcpyDeviceToDevice, stream);
    fill_kernel<<<EDGE_BLOCKS, 256, 0, stream>>>(edges, cursor, csr_src);
    wprep_kernel<<<(16 * 16384 + 255) / 256, 256, 0, stream>>>(W1s, W2s, Wh, Wl);

    hipMemsetAsync(stats8, 0, NLAYERS * 2 * DIM * sizeof(float), stream);

    for (int i = 0; i < NLAYERS; i++) {
        const unsigned short* W1h = Wh + (size_t)(2 * i) * 16384;
        const unsigned short* W1l = Wl + (size_t)(2 * i) * 16384;
        const unsigned short* W2h = Wh + (size_t)(2 * i + 1) * 16384;
        const unsigned short* W2l = Wl + (size_t)(2 * i + 1) * 16384;
        const float* b1 = b1s + (size_t)i * DIM;
        const float* b2 = b2s + (size_t)i * DIM;
        float* stats = stats8 + (size_t)i * 2 * DIM;
        float* ss = ss8 + (size_t)i * 2 * DIM;

        if (i == 0)
            gather_kernel<0><<<NODE_BLOCKS, 256, 0, stream>>>(x, nullptr, offsets, csr_src, hz);
        else
            gather_kernel<1><<<NODE_BLOCKS, 256, 0, stream>>>(z, ss8 + (size_t)(i - 1) * 2 * DIM,
                                                              offsets, csr_src, hz);
        mlp_mfma<<<MLP_BLOCKS, 256, 0, stream>>>(hz, W1h, W1l, b1, W2h, W2l, b2, z);
        bnstats_kernel<<<512, 256, 0, stream>>>(z, stats);
        bnfinalize_kernel<<<1, DIM, 0, stream>>>(stats, gammas + (size_t)i * DIM,
                                                 betas + (size_t)i * DIM, ss);
    }

    gstart_kernel<<<1, 128, 0, stream>>>(batch, gs);
    softmaxc_kernel<<<NODE_BLOCKS, 256, 0, stream>>>(z, ss8 + (size_t)(NLAYERS - 1) * 2 * DIM,
                                                     gum, cout);
    pool_kernel<<<NGRAPHS, 128, 0, stream>>>(cout, gs, pooled);
    head_kernel<<<NGRAPHS, 128, 0, stream>>>(pooled, Wd1, bd1, Wd2, bd2, out);
}

// Round 10
// 1280.064 us; speedup vs baseline: 1.1749x; 1.1749x over previous
//
#include <hip/hip_runtime.h>

#define NN 50000
#define NE 600000
#define DIM 128
#define NLAYERS 8
#define NCLASSES 10
#define NGRAPHS 64
#define BN_EPS 1e-5f
#define SLOPE 0.01f

typedef __attribute__((ext_vector_type(8))) short bf16x8;
typedef __attribute__((ext_vector_type(4))) float f32x4;

__device__ __forceinline__ float lrelu(float v) { return v > 0.f ? v : SLOPE * v; }

__device__ __forceinline__ unsigned short f2bf(float x) {
    unsigned u = __builtin_bit_cast(unsigned, x);
    unsigned r = (u + 0x7FFFu + ((u >> 16) & 1u)) >> 16;
    return (unsigned short)r;
}
__device__ __forceinline__ float bf2f(unsigned short h) {
    return __builtin_bit_cast(float, (unsigned)h << 16);
}
// split x into hi+lo bf16 pair: hi = bf16(x), lo = bf16(x - hi)
__device__ __forceinline__ void split8(const float* __restrict__ p, bf16x8& hi, bf16x8& lo) {
#pragma unroll
    for (int j = 0; j < 8; j++) {
        float x = p[j];
        unsigned short h = f2bf(x);
        hi[j] = (short)h;
        lo[j] = (short)f2bf(x - bf2f(h));
    }
}

// ---------------- CSR build: degree histogram
__global__ __launch_bounds__(256) void degree_kernel(const int* __restrict__ edges,
                                                     int* __restrict__ counts) {
    int e = blockIdx.x * 256 + threadIdx.x;
    if (e >= NE) return;
    atomicAdd(&counts[edges[NE + e]], 1);
}

// ---------------- CSR build: exclusive scan of counts -> offsets (single block)
__global__ __launch_bounds__(1024) void scan_kernel(const int* __restrict__ counts,
                                                    int* __restrict__ offsets) {
    __shared__ int wsum[16];
    __shared__ int carry;
    int lane = threadIdx.x & 63, wid = threadIdx.x >> 6;
    if (threadIdx.x == 0) { carry = 0; offsets[0] = 0; }
    __syncthreads();
    for (int base = 0; base < NN; base += 1024) {
        int i = base + threadIdx.x;
        int v = (i < NN) ? counts[i] : 0;
        int s = v;
#pragma unroll
        for (int o = 1; o < 64; o <<= 1) {
            int t = __shfl_up(s, o);
            if (lane >= o) s += t;
        }
        if (lane == 63) wsum[wid] = s;
        __syncthreads();
        if (wid == 0 && lane < 16) {
            int w = wsum[lane];
            int sw = w;
#pragma unroll
            for (int o = 1; o < 16; o <<= 1) {
                int t = __shfl_up(sw, o);
                if (lane >= o) sw += t;
            }
            wsum[lane] = sw - w;  // exclusive
        }
        __syncthreads();
        int incl = s + wsum[wid] + carry;
        if (i < NN) offsets[i + 1] = incl;
        __syncthreads();
        if (threadIdx.x == 1023) carry = incl;
        __syncthreads();
    }
}

// ---------------- CSR build: fill src lists
__global__ __launch_bounds__(256) void fill_kernel(const int* __restrict__ edges,
                                                   int* __restrict__ cursor,
                                                   int* __restrict__ csr_src) {
    int e = blockIdx.x * 256 + threadIdx.x;
    if (e >= NE) return;
    int d = edges[NE + e];
    int p = atomicAdd(&cursor[d], 1);
    csr_src[p] = edges[e];
}

// ---------------- weight prep: hi/lo bf16 of W^T.  Wt[mat][n][k] = bf16(W[k][n])
__global__ __launch_bounds__(256) void wprep_kernel(const float* __restrict__ W1s,
                                                    const float* __restrict__ W2s,
                                                    unsigned short* __restrict__ Wh,
                                                    unsigned short* __restrict__ Wl) {
    int gid = blockIdx.x * 256 + threadIdx.x;  // 16 * 16384
    if (gid >= 16 * 16384) return;
    int mat = gid >> 14;
    int idx = gid & 16383;
    int n = idx >> 7, k = idx & 127;
    int layer = mat >> 1, which = mat & 1;
    const float* src = which ? (W2s + (size_t)layer * 16384) : (W1s + (size_t)layer * 16384);
    float x = src[k * DIM + n];
    unsigned short h = f2bf(x);
    Wh[gid] = h;
    Wl[gid] = f2bf(x - bf2f(h));
}

// ---------------- gather (+ inline BN finalize + lrelu of producing layer):
// hz[i] = f(z[i]) + sum_{j in N(i)} f(z[j]);  f = BN ? lrelu(z*sc+sh) : z
// ILP form: lane-parallel index fetch + 4-deep row-load unroll.
template <int BN>
__global__ __launch_bounds__(256) void gather_kernel(const float* __restrict__ Zin,
                                                     const float* __restrict__ stats,
                                                     const float* __restrict__ gamma,
                                                     const float* __restrict__ beta,
                                                     const int* __restrict__ offsets,
                                                     const int* __restrict__ csr_src,
                                                     float* __restrict__ hz) {
    int node = blockIdx.x * 4 + (threadIdx.x >> 6);
    if (node >= NN) return;
    int lane = threadIdx.x & 63;
    size_t coloff = (size_t)lane * 2;
    float scx = 0.f, scy = 0.f, shx = 0.f, shy = 0.f;
    if (BN) {
        int c0 = lane * 2, c1 = lane * 2 + 1;
        float mu0 = stats[c0] * (1.f / NN);
        float mu1 = stats[c1] * (1.f / NN);
        float var0 = stats[DIM + c0] * (1.f / NN) - mu0 * mu0;
        float var1 = stats[DIM + c1] * (1.f / NN) - mu1 * mu1;
        scx = gamma[c0] * rsqrtf(var0 + BN_EPS);
        scy = gamma[c1] * rsqrtf(var1 + BN_EPS);
        shx = beta[c0] - mu0 * scx;
        shy = beta[c1] - mu1 * scy;
    }
    int beg = offsets[node], end = offsets[node + 1];
    float2 v = *(const float2*)(Zin + (size_t)node * DIM + coloff);
    float ax, ay;
    if (BN) { ax = lrelu(v.x * scx + shx); ay = lrelu(v.y * scy + shy); }
    else    { ax = v.x; ay = v.y; }

    for (int base = beg; base < end; base += 64) {
        int cnt = min(64, end - base);
        int myidx = (lane < cnt) ? csr_src[base + lane] : 0;
        int e = 0;
        for (; e + 4 <= cnt; e += 4) {
            int i0 = __shfl(myidx, e);
            int i1 = __shfl(myidx, e + 1);
            int i2 = __shfl(myidx, e + 2);
            int i3 = __shfl(myidx, e + 3);
            float2 w0 = *(const float2*)(Zin + (size_t)i0 * DIM + coloff);
            float2 w1 = *(const float2*)(Zin + (size_t)i1 * DIM + coloff);
            float2 w2 = *(const float2*)(Zin + (size_t)i2 * DIM + coloff);
            float2 w3 = *(const float2*)(Zin + (size_t)i3 * DIM + coloff);
            if (BN) {
                ax += lrelu(w0.x * scx + shx) + lrelu(w1.x * scx + shx) +
                      lrelu(w2.x * scx + shx) + lrelu(w3.x * scx + shx);
                ay += lrelu(w0.y * scy + shy) + lrelu(w1.y * scy + shy) +
                      lrelu(w2.y * scy + shy) + lrelu(w3.y * scy + shy);
            } else {
                ax += (w0.x + w1.x) + (w2.x + w3.x);
                ay += (w0.y + w1.y) + (w2.y + w3.y);
            }
        }
        for (; e < cnt; e++) {
            int i0 = __shfl(myidx, e);
            float2 w = *(const float2*)(Zin + (size_t)i0 * DIM + coloff);
            if (BN) { ax += lrelu(w.x * scx + shx); ay += lrelu(w.y * scy + shy); }
            else    { ax += w.x; ay += w.y; }
        }
    }
    float2 o; o.x = ax; o.y = ay;
    *(float2*)(hz + (size_t)node * DIM + coloff) = o;
}

// ---------------- fused MLP on matrix cores, split-bf16 (3-product) precision:
// Z = (lrelu(hz @ W1 + b1)) @ W2 + b2.  hz f32 in, Z f32 out, t1 f32 in LDS.
// 256 thr = 4 waves; wave owns 16 rows x 128 cols; t1 rows wave-private (no barriers).
__global__ __launch_bounds__(256) void mlp_mfma(const float* __restrict__ hz,
                                                const unsigned short* __restrict__ W1h,
                                                const unsigned short* __restrict__ W1l,
                                                const float* __restrict__ b1,
                                                const unsigned short* __restrict__ W2h,
                                                const unsigned short* __restrict__ W2l,
                                                const float* __restrict__ b2,
                                                float* __restrict__ Z) {
    __shared__ float t1[64][132];  // 528B pitch (16B-aligned, 2-way bank alias = free)
    int tid = threadIdx.x;
    int w = tid >> 6, l = tid & 63;
    int l15 = l & 15, kg = l >> 4;
    int rbase = blockIdx.x * 64 + w * 16;
    int mrow = rbase + l15;

    // A fragments (hi/lo) for GEMM1, direct from global f32
    bf16x8 ah[4], al[4];
#pragma unroll
    for (int kb = 0; kb < 4; kb++) {
        float buf[8];
        if (mrow < NN) {
            float4 v0 = *(const float4*)(hz + (size_t)mrow * DIM + kb * 32 + kg * 8);
            float4 v1 = *(const float4*)(hz + (size_t)mrow * DIM + kb * 32 + kg * 8 + 4);
            buf[0] = v0.x; buf[1] = v0.y; buf[2] = v0.z; buf[3] = v0.w;
            buf[4] = v1.x; buf[5] = v1.y; buf[6] = v1.z; buf[7] = v1.w;
        } else {
#pragma unroll
            for (int j = 0; j < 8; j++) buf[j] = 0.f;
        }
        split8(buf, ah[kb], al[kb]);
    }
    // GEMM1: t1 = lrelu(hz @ W1 + b1)   (C: row = kg*4+j, col = nt*16+l15)
#pragma unroll
    for (int nt = 0; nt < 8; nt++) {
        f32x4 acc = {0.f, 0.f, 0.f, 0.f};
#pragma unroll
        for (int kb = 0; kb < 4; kb++) {
            size_t woff = (size_t)(nt * 16 + l15) * DIM + kb * 32 + kg * 8;
            bf16x8 wh = *(const bf16x8*)(W1h + woff);
            bf16x8 wl = *(const bf16x8*)(W1l + woff);
            acc = __builtin_amdgcn_mfma_f32_16x16x32_bf16(ah[kb], wh, acc, 0, 0, 0);
            acc = __builtin_amdgcn_mfma_f32_16x16x32_bf16(ah[kb], wl, acc, 0, 0, 0);
            acc = __builtin_amdgcn_mfma_f32_16x16x32_bf16(al[kb], wh, acc, 0, 0, 0);
        }
        float bias = b1[nt * 16 + l15];
        int colw = nt * 16 + l15;
#pragma unroll
        for (int j = 0; j < 4; j++) {
            t1[w * 16 + kg * 4 + j][colw] = lrelu(acc[j] + bias);
        }
    }
    // A fragments for GEMM2 from LDS (wave-private rows; compiler waits lgkmcnt)
    bf16x8 a2h[4], a2l[4];
#pragma unroll
    for (int kb = 0; kb < 4; kb++) {
        split8(&t1[w * 16 + l15][kb * 32 + kg * 8], a2h[kb], a2l[kb]);
    }
    // GEMM2: Z = t1 @ W2 + b2
#pragma unroll
    for (int nt = 0; nt < 8; nt++) {
        f32x4 acc = {0.f, 0.f, 0.f, 0.f};
#pragma unroll
        for (int kb = 0; kb < 4; kb++) {
            size_t woff = (size_t)(nt * 16 + l15) * DIM + kb * 32 + kg * 8;
            bf16x8 wh = *(const bf16x8*)(W2h + woff);
            bf16x8 wl = *(const bf16x8*)(W2l + woff);
            acc = __builtin_amdgcn_mfma_f32_16x16x32_bf16(a2h[kb], wh, acc, 0, 0, 0);
            acc = __builtin_amdgcn_mfma_f32_16x16x32_bf16(a2h[kb], wl, acc, 0, 0, 0);
            acc = __builtin_amdgcn_mfma_f32_16x16x32_bf16(a2l[kb], wh, acc, 0, 0, 0);
        }
        float bias = b2[nt * 16 + l15];
#pragma unroll
        for (int j = 0; j < 4; j++) {
            int r = rbase + kg * 4 + j;
            if (r < NN) Z[(size_t)r * DIM + nt * 16 + l15] = acc[j] + bias;
        }
    }
}

// ---------------- BN stats: per-col sum & sumsq
__global__ __launch_bounds__(256) void bnstats_kernel(const float* __restrict__ Z,
                                                      float* __restrict__ stats) {
    int col = threadIdx.x & 127;
    int half = threadIdx.x >> 7;
    int stride = gridDim.x * 2;
    float s = 0.f, s2 = 0.f;
    for (int r = blockIdx.x * 2 + half; r < NN; r += stride) {
        float v = Z[(long long)r * DIM + col];
        s += v;
        s2 += v * v;
    }
    __shared__ float red[2][2][DIM];
    red[0][half][col] = s;
    red[1][half][col] = s2;
    __syncthreads();
    if (half == 0) {
        atomicAdd(&stats[col], red[0][0][col] + red[0][1][col]);
        atomicAdd(&stats[DIM + col], red[1][0][col] + red[1][1][col]);
    }
}

// ---------------- graph start offsets (batch sorted)
__global__ void gstart_kernel(const int* __restrict__ batch, int* __restrict__ gs) {
    int g = threadIdx.x;
    if (g > NGRAPHS) return;
    if (g == NGRAPHS) { gs[g] = NN; return; }
    int lo = 0, hi = NN;
    while (lo < hi) {
        int mid = (lo + hi) >> 1;
        if (batch[mid] < g) lo = mid + 1; else hi = mid;
    }
    gs[g] = lo;
}

// ---------------- gumbel softmax per node with inline BN finalize
__global__ __launch_bounds__(256) void softmaxc_kernel(const float* __restrict__ Z,
                                                       const float* __restrict__ stats,
                                                       const float* __restrict__ gamma,
                                                       const float* __restrict__ beta,
                                                       const float* __restrict__ G,
                                                       float* __restrict__ C) {
    int node = blockIdx.x * 4 + (threadIdx.x >> 6);
    if (node >= NN) return;
    int lane = threadIdx.x & 63;
    int c0 = lane * 2, c1 = lane * 2 + 1;
    float mu0 = stats[c0] * (1.f / NN);
    float mu1 = stats[c1] * (1.f / NN);
    float var0 = stats[DIM + c0] * (1.f / NN) - mu0 * mu0;
    float var1 = stats[DIM + c1] * (1.f / NN) - mu1 * mu1;
    float scx = gamma[c0] * rsqrtf(var0 + BN_EPS);
    float scy = gamma[c1] * rsqrtf(var1 + BN_EPS);
    float shx = beta[c0] - mu0 * scx;
    float shy = beta[c1] - mu1 * scy;
    size_t base = (size_t)node * DIM + lane * 2;
    float2 z = *(const float2*)(Z + base);
    float2 gv = *(const float2*)(G + base);
    float vx = z.x * scx + shx + gv.x;
    float vy = z.y * scy + shy + gv.y;
    float m = fmaxf(vx, vy);
#pragma unroll
    for (int o = 32; o >= 1; o >>= 1) m = fmaxf(m, __shfl_xor(m, o));
    float ex = __expf(vx - m), ey = __expf(vy - m);
    float s = ex + ey;
#pragma unroll
    for (int o = 32; o >= 1; o >>= 1) s += __shfl_xor(s, o);
    float inv = 1.f / s;
    float2 c;
    c.x = ex * inv;
    c.y = ey * inv;
    *(float2*)(C + base) = c;
}

// ---------------- pool: block per graph, contiguous column sums
__global__ __launch_bounds__(128) void pool_kernel(const float* __restrict__ C,
                                                   const int* __restrict__ gs,
                                                   float* __restrict__ pooled) {
    int g = blockIdx.x, col = threadIdx.x;
    int beg = gs[g], end = gs[g + 1];
    float a0 = 0.f, a1 = 0.f, a2 = 0.f, a3 = 0.f;
    int r = beg;
    for (; r + 4 <= end; r += 4) {
        a0 += C[(size_t)r * DIM + col];
        a1 += C[(size_t)(r + 1) * DIM + col];
        a2 += C[(size_t)(r + 2) * DIM + col];
        a3 += C[(size_t)(r + 3) * DIM + col];
    }
    for (; r < end; r++) a0 += C[(size_t)r * DIM + col];
    pooled[g * DIM + col] = (a0 + a1) + (a2 + a3);
}

// ---------------- dense head
__global__ __launch_bounds__(128) void head_kernel(const float* __restrict__ pooled,
                                                   const float* __restrict__ Wd1,
                                                   const float* __restrict__ bd1,
                                                   const float* __restrict__ Wd2,
                                                   const float* __restrict__ bd2,
                                                   float* __restrict__ out) {
    int g = blockIdx.x;
    int j = threadIdx.x;
    __shared__ float hid[DIM];
    __shared__ float logits[NCLASSES];
    float acc = bd1[j];
    for (int k = 0; k < DIM; k++) acc += pooled[g * DIM + k] * Wd1[k * DIM + j];
    hid[j] = lrelu(acc);
    __syncthreads();
    if (j < NCLASSES) {
        float a = bd2[j];
        for (int k = 0; k < DIM; k++) a += hid[k] * Wd2[k * NCLASSES + j];
        logits[j] = a;
    }
    __syncthreads();
    if (j == 0) {
        float m = -1e30f;
        for (int c = 0; c < NCLASSES; c++) m = fmaxf(m, logits[c]);
        float s = 0.f, e[NCLASSES];
        for (int c = 0; c < NCLASSES; c++) { e[c] = __expf(logits[c] - m); s += e[c]; }
        float inv = 1.f / s;
        for (int c = 0; c < NCLASSES; c++) out[g * NCLASSES + c] = e[c] * inv;
    }
}

extern "C" void kernel_launch(void* const* d_in, const int* in_sizes, int n_in,
                              void* d_out, int out_size, void* d_ws, size_t ws_size,
                              hipStream_t stream) {
    const float* x = (const float*)d_in[0];
    const int* edges = (const int*)d_in[1];
    const int* batch = (const int*)d_in[2];
    const float* gum = (const float*)d_in[3];
    const float* W1s = (const float*)d_in[4];
    const float* b1s = (const float*)d_in[5];
    const float* W2s = (const float*)d_in[6];
    const float* b2s = (const float*)d_in[7];
    const float* gammas = (const float*)d_in[8];
    const float* betas = (const float*)d_in[9];
    const float* Wd1 = (const float*)d_in[10];
    const float* bd1 = (const float*)d_in[11];
    const float* Wd2 = (const float*)d_in[12];
    const float* bd2 = (const float*)d_in[13];

    float* out = (float*)d_out;
    float* cout = out + NGRAPHS * NCLASSES;

    const size_t ND = (size_t)NN * DIM;
    float* ws = (float*)d_ws;
    float* z = ws;                                   // ND f32 (pre-BN layer output)
    float* hz = z + ND;                              // ND f32 (gather out / MLP in)
    unsigned short* Wh = (unsigned short*)(hz + ND); // 16*16384 bf16 (W^T hi)
    unsigned short* Wl = Wh + 16 * 16384;            // 16*16384 bf16 (W^T lo)
    float* stats8 = (float*)(Wl + 16 * 16384);       // 8 * 2*DIM
    float* pooled = stats8 + NLAYERS * 2 * DIM;      // NGRAPHS*DIM
    int* counts = (int*)(pooled + NGRAPHS * DIM);    // NN
    int* offsets = counts + NN;                      // NN+1
    int* cursor = offsets + NN + 1;                  // NN
    int* csr_src = cursor + NN;                      // NE
    int* gs = csr_src + NE;                          // NGRAPHS+1

    const int MLP_BLOCKS = (NN + 63) / 64;
    const int EDGE_BLOCKS = (NE + 255) / 256;
    const int NODE_BLOCKS = (NN + 3) / 4;

    // ---- CSR build + weight prep (static per launch)
    hipMemsetAsync(counts, 0, NN * sizeof(int), stream);
    degree_kernel<<<EDGE_BLOCKS, 256, 0, stream>>>(edges, counts);
    scan_kernel<<<1, 1024, 0, stream>>>(counts, offsets);
    hipMemcpyAsync(cursor, offsets, NN * sizeof(int), hipMemcpyDeviceToDevice, stream);
    fill_kernel<<<EDGE_BLOCKS, 256, 0, stream>>>(edges, cursor, csr_src);
    wprep_kernel<<<(16 * 16384 + 255) / 256, 256, 0, stream>>>(W1s, W2s, Wh, Wl);

    hipMemsetAsync(stats8, 0, NLAYERS * 2 * DIM * sizeof(float), stream);

    for (int i = 0; i < NLAYERS; i++) {
        const unsigned short* W1h = Wh + (size_t)(2 * i) * 16384;
        const unsigned short* W1l = Wl + (size_t)(2 * i) * 16384;
        const unsigned short* W2h = Wh + (size_t)(2 * i + 1) * 16384;
        const unsigned short* W2l = Wl + (size_t)(2 * i + 1) * 16384;
        const float* b1 = b1s + (size_t)i * DIM;
        const float* b2 = b2s + (size_t)i * DIM;
        float* stats = stats8 + (size_t)i * 2 * DIM;

        if (i == 0)
            gather_kernel<0><<<NODE_BLOCKS, 256, 0, stream>>>(x, nullptr, nullptr, nullptr,
                                                              offsets, csr_src, hz);
        else
            gather_kernel<1><<<NODE_BLOCKS, 256, 0, stream>>>(
                z, stats8 + (size_t)(i - 1) * 2 * DIM, gammas + (size_t)(i - 1) * DIM,
                betas + (size_t)(i - 1) * DIM, offsets, csr_src, hz);
        mlp_mfma<<<MLP_BLOCKS, 256, 0, stream>>>(hz, W1h, W1l, b1, W2h, W2l, b2, z);
        bnstats_kernel<<<512, 256, 0, stream>>>(z, stats);
    }

    gstart_kernel<<<1, 128, 0, stream>>>(batch, gs);
    softmaxc_kernel<<<NODE_BLOCKS, 256, 0, stream>>>(
        z, stats8 + (size_t)(NLAYERS - 1) * 2 * DIM, gammas + (size_t)(NLAYERS - 1) * DIM,
        betas + (size_t)(NLAYERS - 1) * DIM, gum, cout);
    pool_kernel<<<NGRAPHS, 128, 0, stream>>>(cout, gs, pooled);
    head_kernel<<<NGRAPHS, 128, 0, stream>>>(pooled, Wd1, bd1, Wd2, bd2, out);
}